// Round 1
// baseline (99.992 us; speedup 1.0000x reference)
//
#include <hip/hip_runtime.h>
#include <math.h>

// GeometricEmbedding: B=4, N=M=3000, d_model=2, sigma_d=1.0
// out[0 .. B*N*2)        = p0_emb  (p0 * [sum_m sin(d), sum_m cos(d)])
// out[B*N*2 .. +B*M*2)   = p1_emb  (p1 * [sum_n sin(d), sum_n cos(d)])
// d[b,n,m] = sqrt(max(2 - 2*(p0.p1), 0))

#define GB 4
#define GN 3000
#define GM 3000
#define ROWS_PER_BLOCK 4   // one wave per output row, 4 waves (256 thr) per block

__global__ __launch_bounds__(256) void geo_emb_kernel(
    const float* __restrict__ p0,
    const float* __restrict__ p1,
    float* __restrict__ out)
{
    const int wave = threadIdx.x >> 6;
    const int lane = threadIdx.x & 63;

    const int nRowBlocks = (GB * GN) / ROWS_PER_BLOCK;  // 3000

    const float* own;
    const float* other;
    float* o;
    int row_global;
    int otherCount;

    if (blockIdx.x < nRowBlocks) {
        // p0-side: sum over m (partner set = p1)
        row_global = blockIdx.x * ROWS_PER_BLOCK + wave;   // in [0, GB*GN)
        own = p0; other = p1; o = out;
        otherCount = GM;
    } else {
        // p1-side: sum over n (partner set = p0)
        row_global = (blockIdx.x - nRowBlocks) * ROWS_PER_BLOCK + wave;
        own = p1; other = p0; o = out + GB * GN * 2;
        otherCount = GN;
    }

    const int b = row_global / GN;      // const divide -> magic mul
    const float2 pr = ((const float2*)own)[row_global];
    const float2* __restrict__ obase = ((const float2*)other) + b * otherCount;

    float ssum = 0.0f;
    float csum = 0.0f;

    for (int m = lane; m < otherCount; m += 64) {
        float2 q = obase[m];
        float dot = fmaf(pr.x, q.x, pr.y * q.y);
        float t = fmaxf(fmaf(-2.0f, dot, 2.0f), 0.0f);
        float d = __builtin_amdgcn_sqrtf(t);   // raw v_sqrt_f32
        ssum += __sinf(d);                     // v_sin_f32 (arg * 1/2pi)
        csum += __cosf(d);                     // v_cos_f32
    }

    // wave(64) butterfly reduction
    #pragma unroll
    for (int off = 32; off >= 1; off >>= 1) {
        ssum += __shfl_down(ssum, off, 64);
        csum += __shfl_down(csum, off, 64);
    }

    if (lane == 0) {
        float2 res;
        res.x = pr.x * ssum;
        res.y = pr.y * csum;
        ((float2*)o)[row_global] = res;
    }
}

extern "C" void kernel_launch(void* const* d_in, const int* in_sizes, int n_in,
                              void* d_out, int out_size, void* d_ws, size_t ws_size,
                              hipStream_t stream) {
    const float* points0 = (const float*)d_in[0];
    const float* points1 = (const float*)d_in[1];
    float* out = (float*)d_out;

    const int nRowBlocks = (GB * GN) / ROWS_PER_BLOCK;   // 3000
    const int nColBlocks = (GB * GM) / ROWS_PER_BLOCK;   // 3000
    dim3 grid(nRowBlocks + nColBlocks);
    dim3 block(256);
    geo_emb_kernel<<<grid, block, 0, stream>>>(points0, points1, out);
}

// Round 2
// 87.650 us; speedup vs baseline: 1.1408x; 1.1408x over previous
//
#include <hip/hip_runtime.h>
#include <math.h>

// GeometricEmbedding: B=4, N=M=3000, d_model=2, sigma_d=1.0
// out[0 .. B*N*2)        = p0_emb  (p0 * [sum_m sin(d), sum_m cos(d)])
// out[B*N*2 .. +B*M*2)   = p1_emb  (p1 * [sum_n sin(d), sum_n cos(d)])
// d[b,n,m] = sqrt(max(2 - 2*(p0.p1), 0))
//
// Issue-bound on the transcendental pipe (v_sqrt+v_sin+v_cos = 24 cyc/wave-iter).
// R1 showed VALUBusy=52% @ VGPR=8: dependent load->sqrt->sin chain each iter.
// This version: unroll x4 with independent accumulators to fill the pipe.

#define GB 4
#define GN 3000
#define GM 3000
#define ROWS_PER_BLOCK 4   // one wave per output row, 4 waves (256 thr) per block

#define INV2PI 0.15915494309189535f

__device__ __forceinline__ void pair_acc(float2 q, float px, float py,
                                         float& s, float& c) {
    float dot = fmaf(px, q.x, py * q.y);
    float t   = fmaxf(fmaf(-2.0f, dot, 2.0f), 0.0f);
    float d   = __builtin_amdgcn_sqrtf(t);       // v_sqrt_f32
    float r   = d * INV2PI;                      // shared scale for sin+cos
    s += __builtin_amdgcn_sinf(r);               // raw v_sin_f32 (revolutions)
    c += __builtin_amdgcn_cosf(r);               // raw v_cos_f32
}

__global__ __launch_bounds__(256) void geo_emb_kernel(
    const float* __restrict__ p0,
    const float* __restrict__ p1,
    float* __restrict__ out)
{
    const int wave = threadIdx.x >> 6;
    const int lane = threadIdx.x & 63;

    const int nRowBlocks = (GB * GN) / ROWS_PER_BLOCK;  // 3000

    const float* own;
    const float* other;
    float* o;
    int row_global;

    if (blockIdx.x < nRowBlocks) {
        row_global = blockIdx.x * ROWS_PER_BLOCK + wave;
        own = p0; other = p1; o = out;
    } else {
        row_global = (blockIdx.x - nRowBlocks) * ROWS_PER_BLOCK + wave;
        own = p1; other = p0; o = out + GB * GN * 2;
    }

    const int b = row_global / GN;                 // magic-mul
    const float2 pr = ((const float2*)own)[row_global];
    const float px = pr.x, py = pr.y;
    const float2* __restrict__ obase = ((const float2*)other) + b * GM;

    // 3000 partners per lane-stride-64: i = 0..45 full (2944), i=46 partial (56)
    float s0 = 0.f, s1 = 0.f, s2 = 0.f, s3 = 0.f;
    float c0 = 0.f, c1 = 0.f, c2 = 0.f, c3 = 0.f;

    int i = 0;
    #pragma unroll 1
    for (; i < 44; i += 4) {                       // 11 loops of 4 indep chains
        float2 q0 = obase[lane + (i + 0) * 64];
        float2 q1 = obase[lane + (i + 1) * 64];
        float2 q2 = obase[lane + (i + 2) * 64];
        float2 q3 = obase[lane + (i + 3) * 64];
        pair_acc(q0, px, py, s0, c0);
        pair_acc(q1, px, py, s1, c1);
        pair_acc(q2, px, py, s2, c2);
        pair_acc(q3, px, py, s3, c3);
    }
    {                                              // i = 44, 45 (full)
        float2 q0 = obase[lane + 44 * 64];
        float2 q1 = obase[lane + 45 * 64];
        pair_acc(q0, px, py, s0, c0);
        pair_acc(q1, px, py, s1, c1);
    }
    if (lane < 56) {                               // i = 46 (tail: 2944..2999)
        float2 q0 = obase[lane + 46 * 64];
        pair_acc(q0, px, py, s2, c2);
    }

    float ssum = (s0 + s1) + (s2 + s3);
    float csum = (c0 + c1) + (c2 + c3);

    #pragma unroll
    for (int off = 32; off >= 1; off >>= 1) {
        ssum += __shfl_down(ssum, off, 64);
        csum += __shfl_down(csum, off, 64);
    }

    if (lane == 0) {
        float2 res;
        res.x = px * ssum;
        res.y = py * csum;
        ((float2*)o)[row_global] = res;
    }
}

extern "C" void kernel_launch(void* const* d_in, const int* in_sizes, int n_in,
                              void* d_out, int out_size, void* d_ws, size_t ws_size,
                              hipStream_t stream) {
    const float* points0 = (const float*)d_in[0];
    const float* points1 = (const float*)d_in[1];
    float* out = (float*)d_out;

    dim3 grid(2 * (GB * GN) / ROWS_PER_BLOCK);     // 6000
    dim3 block(256);
    geo_emb_kernel<<<grid, block, 0, stream>>>(points0, points1, out);
}